// Round 4
// baseline (643.792 us; speedup 1.0000x reference)
//
#include <hip/hip_runtime.h>
#include <hip/hip_fp16.h>

typedef _Float16 f16x4 __attribute__((ext_vector_type(4)));
typedef _Float16 f16x8 __attribute__((ext_vector_type(8)));
typedef float    f32x4 __attribute__((ext_vector_type(4)));

#define TBD 67108864ull   // T*B*D
#define BD  1048576ull    // B*D

#define ASM_VMCNT(N) asm volatile("s_waitcnt vmcnt(" #N ")" ::: "memory")
#define ASM_LGKM(N)  asm volatile("s_waitcnt lgkmcnt(" #N ")" ::: "memory")
#define BARRIER()    __builtin_amdgcn_s_barrier()
#define SCHED0()     __builtin_amdgcn_sched_barrier(0)
#define MFMA(a,b,c)  __builtin_amdgcn_mfma_f32_16x16x32_f16((a),(b),(c),0,0,0)

// ---------------- Kernel 1: se = (pred-true)^2, split into fp16 hi/lo ----------------
__global__ __launch_bounds__(256) void se_split_k(const float* __restrict__ pred,
                                                  const float* __restrict__ tru,
                                                  _Float16* __restrict__ hi,
                                                  _Float16* __restrict__ lo) {
  size_t stride = (size_t)gridDim.x * 1024;
  for (size_t i = ((size_t)blockIdx.x * 256 + threadIdx.x) * 4; i < TBD; i += stride) {
    float4 p = *(const float4*)(pred + i);
    float4 t = *(const float4*)(tru + i);
    float s0 = (p.x - t.x) * (p.x - t.x);
    float s1 = (p.y - t.y) * (p.y - t.y);
    float s2 = (p.z - t.z) * (p.z - t.z);
    float s3 = (p.w - t.w) * (p.w - t.w);
    f16x4 h, l;
    h[0] = (_Float16)s0; l[0] = (_Float16)(s0 - (float)h[0]);
    h[1] = (_Float16)s1; l[1] = (_Float16)(s1 - (float)h[1]);
    h[2] = (_Float16)s2; l[2] = (_Float16)(s2 - (float)h[2]);
    h[3] = (_Float16)s3; l[3] = (_Float16)(s3 - (float)h[3]);
    *(f16x4*)(hi + i) = h;
    *(f16x4*)(lo + i) = l;
  }
}

// ---------------- Kernel 2: split W into fp16 hi/lo ----------------
__global__ __launch_bounds__(256) void w_split_k(const float* __restrict__ W,
                                                 _Float16* __restrict__ hi,
                                                 _Float16* __restrict__ lo) {
  size_t i = ((size_t)blockIdx.x * 256 + threadIdx.x) * 4;  // covers 1048576 exactly
  float4 x = *(const float4*)(W + i);
  f16x4 h, l;
  h[0] = (_Float16)x.x; l[0] = (_Float16)(x.x - (float)h[0]);
  h[1] = (_Float16)x.y; l[1] = (_Float16)(x.y - (float)h[1]);
  h[2] = (_Float16)x.z; l[2] = (_Float16)(x.z - (float)h[2]);
  h[3] = (_Float16)x.w; l[3] = (_Float16)(x.w - (float)h[3]);
  *(f16x4*)(hi + i) = h;
  *(f16x4*)(lo + i) = l;
}

// ---------------- Kernel 3: logits = SE @ W^T + b (split-fp16 3-pass, 8-phase schedule) ---
// M=65536, N=1024, K=1024. Tile 256x256, BK=32, 8 waves (2M x 4N), per-wave 128x64.
// LDS: 2 buffers x 64KB; buffer = A[256 rows][128B] + B[256 rows][128B].
// Row = 8 x 16B slots: slots 0-3 = hi(k0..31), 4-7 = lo; physical slot = logical ^ (row&7).
// K-loop: 4 phases per tile (quadrants), per-phase {reads; barrier; lgkm(0); sched0;
// setprio MFMA setprio; barrier}; staging clump in P3 (reads of buffer done by P2 tail);
// counted vmcnt(8) once per tile (2-deep prefetch, never drained in main loop).

// 24 MFMAs = quadrant (4 fi x 2 fj x 3 passes), pass-major: 8 independent accs per pass.
#define MFMA_Q(f0, j0, AH0, AL0, AH1, AL1, AH2, AL2, AH3, AL3)            \
  __builtin_amdgcn_s_setprio(1);                                          \
  _Pragma("unroll")                                                       \
  for (int jj = 0; jj < 2; ++jj) {                                        \
    acc[(f0)+0][(j0)+jj] = MFMA(AH0, bh[(j0)+jj], acc[(f0)+0][(j0)+jj]);  \
    acc[(f0)+1][(j0)+jj] = MFMA(AH1, bh[(j0)+jj], acc[(f0)+1][(j0)+jj]);  \
    acc[(f0)+2][(j0)+jj] = MFMA(AH2, bh[(j0)+jj], acc[(f0)+2][(j0)+jj]);  \
    acc[(f0)+3][(j0)+jj] = MFMA(AH3, bh[(j0)+jj], acc[(f0)+3][(j0)+jj]);  \
  }                                                                       \
  _Pragma("unroll")                                                       \
  for (int jj = 0; jj < 2; ++jj) {                                        \
    acc[(f0)+0][(j0)+jj] = MFMA(AL0, bh[(j0)+jj], acc[(f0)+0][(j0)+jj]);  \
    acc[(f0)+1][(j0)+jj] = MFMA(AL1, bh[(j0)+jj], acc[(f0)+1][(j0)+jj]);  \
    acc[(f0)+2][(j0)+jj] = MFMA(AL2, bh[(j0)+jj], acc[(f0)+2][(j0)+jj]);  \
    acc[(f0)+3][(j0)+jj] = MFMA(AL3, bh[(j0)+jj], acc[(f0)+3][(j0)+jj]);  \
  }                                                                       \
  _Pragma("unroll")                                                       \
  for (int jj = 0; jj < 2; ++jj) {                                        \
    acc[(f0)+0][(j0)+jj] = MFMA(AH0, bl[(j0)+jj], acc[(f0)+0][(j0)+jj]);  \
    acc[(f0)+1][(j0)+jj] = MFMA(AH1, bl[(j0)+jj], acc[(f0)+1][(j0)+jj]);  \
    acc[(f0)+2][(j0)+jj] = MFMA(AH2, bl[(j0)+jj], acc[(f0)+2][(j0)+jj]);  \
    acc[(f0)+3][(j0)+jj] = MFMA(AH3, bl[(j0)+jj], acc[(f0)+3][(j0)+jj]);  \
  }                                                                       \
  __builtin_amdgcn_s_setprio(0);

#define STAGE8(kof, dst)                                                         \
  _Pragma("unroll")                                                              \
  for (int q = 0; q < 4; ++q) {                                                  \
    __builtin_amdgcn_global_load_lds(                                            \
        (const __attribute__((address_space(1))) void*)(aSrc[q] + (kof)),        \
        (__attribute__((address_space(3))) void*)((dst) + q * 8192 + tid * 16),  \
        16, 0, 0);                                                               \
    __builtin_amdgcn_global_load_lds(                                            \
        (const __attribute__((address_space(1))) void*)(bSrc[q] + (kof)),        \
        (__attribute__((address_space(3))) void*)((dst) + 32768 + q * 8192 + tid * 16), \
        16, 0, 0);                                                               \
  }

__global__ __launch_bounds__(512, 2) void gemm_logits_k(
    const _Float16* __restrict__ Ah, const _Float16* __restrict__ Al,
    const _Float16* __restrict__ Wh, const _Float16* __restrict__ Wl,
    const float* __restrict__ bias, float* __restrict__ C) {
  __shared__ uint4 lds4[8192];  // 128 KiB
  char* lds = (char*)lds4;
  const int tid = threadIdx.x;
  const int lane = tid & 63;
  const int wid = tid >> 6;          // 0..7
  const int wr = wid >> 2;           // 0..1 (M)
  const int wc = wid & 3;            // 0..3 (N)

  // XCD-aware bijective swizzle: 1024 blocks, 8 XCDs, 128 per XCD.
  const int bid = blockIdx.x;
  const int wgid = (bid & 7) * 128 + (bid >> 3);
  const int bm = wgid >> 2, bn = wgid & 3;   // 256 M-tiles x 4 N-tiles
  const int row0 = bm * 256, col0 = bn * 256;

  // Staging source addresses (inverse-swizzled), 4 A + 4 B chunks of 16B per thread.
  const _Float16* aSrc[4];
  const _Float16* bSrc[4];
#pragma unroll
  for (int q = 0; q < 4; ++q) {
    int p = q * 8192 + tid * 16;      // byte offset in 32KB region
    int r = p >> 7;                   // row 0..255
    int s = (p >> 4) & 7;             // physical slot
    int sig = s ^ (r & 7);            // logical slot
    size_t koff = (size_t)(sig & 3) * 8;
    aSrc[q] = (sig < 4 ? Ah : Al) + ((size_t)(row0 + r) * 1024 + koff);
    bSrc[q] = (sig < 4 ? Wh : Wl) + ((size_t)(col0 + r) * 1024 + koff);
  }

  // Fragment read offsets (within a buffer).
  const int u = lane >> 4;           // 0..3 -> k = 8u
  const int sw = lane & 7;
  const int aRow = wr * 128 + (lane & 15);
  const int bRow = wc * 64 + (lane & 15);
  const int aoffH = aRow * 128 + ((u)     ^ sw) * 16;
  const int aoffL = aRow * 128 + ((u + 4) ^ sw) * 16;
  const int boffH = 32768 + bRow * 128 + ((u)     ^ sw) * 16;
  const int boffL = 32768 + bRow * 128 + ((u + 4) ^ sw) * 16;

  f32x4 acc[8][4] = {};

  // Prologue: stage tile 0 -> buf0, tile 1 -> buf1; wait tile 0 (tile 1 in flight).
  STAGE8(0, lds)
  STAGE8(32, lds + 65536)
  ASM_VMCNT(8);
  BARRIER();

#pragma unroll 1
  for (int t = 0; t < 32; ++t) {
    char* ldsb = lds + (t & 1) * 65536;
    const int tt = (t + 2 < 32) ? t + 2 : 31;       // dummy tail reload keeps vmcnt uniform
    const size_t kof = (size_t)tt * 32;

    // ---------- P0: read B01 + A0-3; MFMA fi0-3 x fj0-1 ----------
    f16x8 bh[4], bl[4];
    bh[0] = *(const f16x8*)(ldsb + boffH + 0 * 2048);
    bl[0] = *(const f16x8*)(ldsb + boffL + 0 * 2048);
    bh[1] = *(const f16x8*)(ldsb + boffH + 1 * 2048);
    bl[1] = *(const f16x8*)(ldsb + boffL + 1 * 2048);
    f16x8 aH0 = *(const f16x8*)(ldsb + aoffH + 0 * 2048);
    f16x8 aL0 = *(const f16x8*)(ldsb + aoffL + 0 * 2048);
    f16x8 aH1 = *(const f16x8*)(ldsb + aoffH + 1 * 2048);
    f16x8 aL1 = *(const f16x8*)(ldsb + aoffL + 1 * 2048);
    f16x8 aH2 = *(const f16x8*)(ldsb + aoffH + 2 * 2048);
    f16x8 aL2 = *(const f16x8*)(ldsb + aoffL + 2 * 2048);
    f16x8 aH3 = *(const f16x8*)(ldsb + aoffH + 3 * 2048);
    f16x8 aL3 = *(const f16x8*)(ldsb + aoffL + 3 * 2048);
    BARRIER();
    ASM_LGKM(0);
    SCHED0();
    MFMA_Q(0, 0, aH0, aL0, aH1, aL1, aH2, aL2, aH3, aL3)
    BARRIER();

    // ---------- P1: read B23; MFMA fi0-3 x fj2-3 ----------
    bh[2] = *(const f16x8*)(ldsb + boffH + 2 * 2048);
    bl[2] = *(const f16x8*)(ldsb + boffL + 2 * 2048);
    bh[3] = *(const f16x8*)(ldsb + boffH + 3 * 2048);
    bl[3] = *(const f16x8*)(ldsb + boffL + 3 * 2048);
    BARRIER();
    ASM_LGKM(0);
    SCHED0();
    MFMA_Q(0, 2, aH0, aL0, aH1, aL1, aH2, aL2, aH3, aL3)
    BARRIER();

    // ---------- P2: read A4-7; MFMA fi4-7 x fj2-3 ----------
    f16x8 aH4 = *(const f16x8*)(ldsb + aoffH + 4 * 2048);
    f16x8 aL4 = *(const f16x8*)(ldsb + aoffL + 4 * 2048);
    f16x8 aH5 = *(const f16x8*)(ldsb + aoffH + 5 * 2048);
    f16x8 aL5 = *(const f16x8*)(ldsb + aoffL + 5 * 2048);
    f16x8 aH6 = *(const f16x8*)(ldsb + aoffH + 6 * 2048);
    f16x8 aL6 = *(const f16x8*)(ldsb + aoffL + 6 * 2048);
    f16x8 aH7 = *(const f16x8*)(ldsb + aoffH + 7 * 2048);
    f16x8 aL7 = *(const f16x8*)(ldsb + aoffL + 7 * 2048);
    BARRIER();
    ASM_LGKM(0);
    SCHED0();
    MFMA_Q(4, 2, aH4, aL4, aH5, aL5, aH6, aL6, aH7, aL7)
    BARRIER();     // after this barrier every wave's reads of ldsb have returned

    // ---------- P3: stage tile t+2 into ldsb; MFMA fi4-7 x fj0-1 ----------
    STAGE8(kof, ldsb)
    SCHED0();      // keep stage-issue ahead of the MFMA cluster
    MFMA_Q(4, 0, aH4, aL4, aH5, aL5, aH6, aL6, aH7, aL7)
    ASM_VMCNT(8);  // tile t+1's 8 loads landed (t+2's 8 still in flight)
    BARRIER();
  }
  ASM_VMCNT(0);    // drain tail dummy loads

  // Epilogue: C[i,j] = acc + bias[j].  C/D: col=lane&15, row=(lane>>4)*4+q.
#pragma unroll
  for (int fj = 0; fj < 4; ++fj) {
    int c = col0 + wc * 64 + fj * 16 + (lane & 15);
    float bj = bias[c];
#pragma unroll
    for (int fi = 0; fi < 8; ++fi) {
      int r = row0 + wr * 128 + fi * 16 + u * 4;
#pragma unroll
      for (int q = 0; q < 4; ++q)
        C[(size_t)(r + q) * 1024 + c] = acc[fi][fj][q] + bj;
    }
  }
}

// ---------------- Kernel 4: fused softmax + gating + loss accumulation ----------------
// Block = batch row b. Loops t=0..63 keeping w_prev (gating weight) and loss acc in regs.
__global__ __launch_bounds__(256) void softmax_loss_k(const float* __restrict__ logits,
                                                      const _Float16* __restrict__ hi,
                                                      const _Float16* __restrict__ lo,
                                                      float* __restrict__ out) {
  const int b = blockIdx.x;            // 0..1023
  const int tid = threadIdx.x, lane = tid & 63, wid = tid >> 6;
  __shared__ float red[8];
  float4 wprev = make_float4(1.f, 1.f, 1.f, 1.f);
  float4 lacc  = make_float4(0.f, 0.f, 0.f, 0.f);

  size_t base = (size_t)b * 1024;      // row (t=0, b)
  float4 x = ((const float4*)(logits + base))[tid];
  f16x4  h = ((const f16x4*)(hi + base))[tid];
  f16x4  l = ((const f16x4*)(lo + base))[tid];

#pragma unroll 1
  for (int t = 0; t < 64; ++t) {
    float4 se;
    se.x = (float)h[0] + (float)l[0];
    se.y = (float)h[1] + (float)l[1];
    se.z = (float)h[2] + (float)l[2];
    se.w = (float)h[3] + (float)l[3];
    lacc.x += wprev.x * se.x;
    lacc.y += wprev.y * se.y;
    lacc.z += wprev.z * se.z;
    lacc.w += wprev.w * se.w;

    // prefetch next row (hide HBM latency under the softmax reduces)
    int tn = (t + 1 < 64) ? t + 1 : t;
    size_t nbase = ((size_t)tn * 1024 + (size_t)b) * 1024;
    float4 xn = ((const float4*)(logits + nbase))[tid];
    f16x4  hn = ((const f16x4*)(hi + nbase))[tid];
    f16x4  ln = ((const f16x4*)(lo + nbase))[tid];

    float m = fmaxf(fmaxf(x.x, x.y), fmaxf(x.z, x.w));
#pragma unroll
    for (int o = 32; o >= 1; o >>= 1) m = fmaxf(m, __shfl_xor(m, o, 64));
    if (lane == 0) red[wid] = m;
    __syncthreads();
    m = fmaxf(fmaxf(red[0], red[1]), fmaxf(red[2], red[3]));
    float e0 = __expf(x.x - m), e1 = __expf(x.y - m), e2 = __expf(x.z - m), e3 = __expf(x.w - m);
    float s = (e0 + e1) + (e2 + e3);
#pragma unroll
    for (int o = 32; o >= 1; o >>= 1) s += __shfl_xor(s, o, 64);
    if (lane == 0) red[4 + wid] = s;
    __syncthreads();
    s = (red[4] + red[5]) + (red[6] + red[7]);
    float inv = 1.0f / s;

    wprev.x = se.x * e0 * inv;
    wprev.y = se.y * e1 * inv;
    wprev.z = se.z * e2 * inv;
    wprev.w = se.w * e3 * inv;

    x = xn; h = hn; l = ln;
  }
  ((float4*)(out + (size_t)b * 1024))[tid] = lacc;
}

extern "C" void kernel_launch(void* const* d_in, const int* in_sizes, int n_in,
                              void* d_out, int out_size, void* d_ws, size_t ws_size,
                              hipStream_t stream) {
  const float* pred = (const float*)d_in[0];
  const float* tru  = (const float*)d_in[1];
  const float* W    = (const float*)d_in[2];
  const float* bias = (const float*)d_in[3];
  float* out = (float*)d_out;

  char* ws = (char*)d_ws;
  _Float16* se_hi  = (_Float16*)(ws);                    // 128 MB
  _Float16* se_lo  = (_Float16*)(ws + 134217728ull);     // 128 MB
  float*    logits = (float*)   (ws + 268435456ull);     // 256 MB
  _Float16* W_hi   = (_Float16*)(ws + 536870912ull);     // 2 MB
  _Float16* W_lo   = (_Float16*)(ws + 538968064ull);     // 2 MB

  se_split_k<<<2048, 256, 0, stream>>>(pred, tru, se_hi, se_lo);
  w_split_k<<<1024, 256, 0, stream>>>(W, W_hi, W_lo);
  gemm_logits_k<<<1024, 512, 0, stream>>>(se_hi, se_lo, W_hi, W_lo, bias, logits);
  softmax_loss_k<<<1024, 256, 0, stream>>>(logits, se_hi, se_lo, out);
}